// Round 7
// baseline (982.283 us; speedup 1.0000x reference)
//
#include <hip/hip_runtime.h>
#include <hip/hip_bf16.h>

// EdgePredictor: gather-concat -> Linear(320->256) -> BatchNorm(train) ->
// Linear(256->8) -> LogSoftmax.  All float tensors FP32; output FP32.
// Indices int32 or int64 -> runtime detect.
//
// Algebra: logits = h @ M^T + C,  M = W2*diag(g')*W1 (8x320).
// Split along concat:  logits_e = ef_e @ Me^T + Ps[src_e] + Pd[dst_e] + C
//   Ps = nf @ Ms^T, Pd = nf @ Md^T  (50000x8 tables)
//
// Big-ws fast path = 4 dispatches:
//   1. prep_all: nf->bf16, W1->bf16, zero stats, detect idx width
//   2. gemm1_stats: 128-edge x 256-col tile, 512 threads (8 waves),
//      wave = (rowhalf, 64-col group): r=2/c=4 decomposition halves the
//      per-CU LDS A-read volume (the measured top pipe consumer) vs r5's
//      c=8; each ds_read_b128 now feeds 4 MFMA.  80KB swizzled LDS, one
//      barrier, 2-deep B register prefetch.
//   3. fold_nodeproj: fold + node projection (x8-unrolled hh loops).
//   4. edge_out: ef GEMM (K=64 MFMA) + per-lane table gather; LDS-transpose
//      epilogue (pad 20: no read aliasing), per-lane serial softmax,
//      coalesced float4 stores.
// Round-6 lesson: table-memoization of the stats pass (B/C row gathers)
// loses to MFMA recompute (245 vs 188 us) -> reverted.
// Fallback paths for smaller ws kept.

#define N_EDGES 800000
#define N_NODES 50000

typedef __attribute__((ext_vector_type(8))) short short8;
typedef __attribute__((ext_vector_type(4))) float f32x4;

// ws layout (bytes)
#define WS_SUM   0         // 16 slots x 256 f32 = 16384
#define WS_SQ    16384     // 16384
#define WS_CVEC  32768     // 16 f32
#define WS_FLAG  32832     // 1 int (zero region ends at 33280)
#define WS_MBIG  33280     // 16 x 320 bf16 = 10240 (fallback path)
#define WS_MB    43520     // 16 x 64 bf16 = 2048 (edge part)
#define WS_MF    45568     // 8 x 320 f32 = 10240 (fallback path)
#define WS_W1B   55808     // 256 x 320 bf16 = 163840 -> 219648
#define WS_PS    262144    // 50000 x 8 f32 = 1600000
#define WS_PD    2097152   // 1600000
#define WS_NFB   4194304   // 50000 x 128 bf16 = 12800000 -> 16994304
#define WS_FAST_NEED (4u << 20)
#define WS_BIG_NEED  16994304u

__device__ __forceinline__ ushort f2bf(float f) {
    union { float f; unsigned int u; } x; x.f = f;
    unsigned int r = x.u + 0x7FFFu + ((x.u >> 16) & 1u);   // RNE
    return (ushort)(r >> 16);
}
__device__ __forceinline__ short8 cvt8(const float* __restrict__ p) {
    short8 r;
    #pragma unroll
    for (int i = 0; i < 8; i++) r[i] = (short)f2bf(p[i]);
    return r;
}
__device__ __forceinline__ short8 cvtpair(uint4 a, uint4 b) {
    unsigned int v[8] = {a.x, a.y, a.z, a.w, b.x, b.y, b.z, b.w};
    short8 r;
    #pragma unroll
    for (int i = 0; i < 8; i++) {
        unsigned int u = v[i];
        unsigned int rr = u + 0x7FFFu + ((u >> 16) & 1u);
        r[i] = (short)(rr >> 16);
    }
    return r;
}

// XOR-swizzled LDS index (ushort units) for slice s (0..9), row r (0..127),
// 16B-slot c (0..3).  Row stride 64B.  slot' = c ^ ((r>>1)&3): wave reads
// (16 rows x 4 quads) and wave writes (16 rows x 4 chunks) both uniform
// over banks.  Same function both sides; 0 conflicts measured (r2-r5).
__device__ __forceinline__ int aidx(int s, int r, int c) {
    return ((s * 128 + r) * 4 + (c ^ ((r >> 1) & 3))) * 8;
}

// -------- detect index width: int64 iff all sampled high words are zero ----
__global__ void detect_kernel(const int* __restrict__ src,
                              const int* __restrict__ dst, int* flag) {
    int t = threadIdx.x;
    int v = src[2 * t + 1] | dst[2 * t + 1];
    #pragma unroll
    for (int o = 32; o >= 1; o >>= 1) v |= __shfl_xor(v, o);
    if (t == 0) *flag = (v == 0) ? 1 : 0;
}

// -------- prep: W1 f32 -> bf16 (fallback path) --------
__global__ __launch_bounds__(256) void prep_kernel(const float* __restrict__ W1,
                                                   ushort* __restrict__ W1b) {
    const int i = (blockIdx.x * 256 + threadIdx.x) * 4;
    const float4 v = *(const float4*)(W1 + i);
    ushort4 o;
    o.x = f2bf(v.x); o.y = f2bf(v.y); o.z = f2bf(v.z); o.w = f2bf(v.w);
    *(ushort4*)(W1b + i) = o;
}

// -------- prep_all (big path): nf cvt + W1 cvt + zero + detect ------------
__global__ __launch_bounds__(256) void prep_all_kernel(
    const float* __restrict__ nf, const float* __restrict__ W1,
    const int* __restrict__ src, const int* __restrict__ dst,
    ushort* __restrict__ nfb, ushort* __restrict__ W1b,
    float* __restrict__ zreg, int* __restrict__ flag)
{
    const int t = threadIdx.x;
    const int b = blockIdx.x;
    if (b < 3125) {
        const long i = (long)b * 2048 + t * 8;
        const float4 v0 = *(const float4*)(nf + i);
        const float4 v1 = *(const float4*)(nf + i + 4);
        short8 o;
        o[0] = (short)f2bf(v0.x); o[1] = (short)f2bf(v0.y);
        o[2] = (short)f2bf(v0.z); o[3] = (short)f2bf(v0.w);
        o[4] = (short)f2bf(v1.x); o[5] = (short)f2bf(v1.y);
        o[6] = (short)f2bf(v1.z); o[7] = (short)f2bf(v1.w);
        *(short8*)(nfb + i) = o;
    } else if (b < 3205) {
        const int i = (b - 3125) * 1024 + t * 4;
        const float4 v = *(const float4*)(W1 + i);
        ushort4 o;
        o.x = f2bf(v.x); o.y = f2bf(v.y); o.z = f2bf(v.z); o.w = f2bf(v.w);
        *(ushort4*)(W1b + i) = o;
    } else {
        for (int i = t; i < 8320; i += 256) zreg[i] = 0.f;
        __syncthreads();
        if (t < 64) {
            int v = src[2 * t + 1] | dst[2 * t + 1];
            #pragma unroll
            for (int o = 32; o >= 1; o >>= 1) v |= __shfl_xor(v, o);
            if (t == 0) *flag = (v == 0) ? 1 : 0;
        }
    }
}

// ---------------- Kernel A: gather + GEMM1 + column stats ----------------
// grid 6250, block 512 (8 waves).  Tile 128 edges x 256 cols, K=320 in
// 10x32.  Wave w: row-half h=w>>2 (64 rows), col-group g=w&3 (64 cols).
// Per K-step per wave: 4 ds_read_b128 (A) + 4 B-frag (2-deep L2 prefetch)
// -> 16 MFMA.  LDS A-read volume per CU halved vs round-5 (the top pipe
// consumer); B L2 traffic doubles but starts lower.
template <bool NFB>
__global__ __launch_bounds__(512, 4) void gemm1_stats_kernel(
    const float* __restrict__ nf, const ushort* __restrict__ nfb,
    const float* __restrict__ ef,
    const int* __restrict__ src, const int* __restrict__ dst,
    const ushort* __restrict__ W1b, const int* __restrict__ flag,
    float* __restrict__ g_sum, float* __restrict__ g_sq)
{
    __shared__ ushort a_lds[10 * 128 * 32];     // 81920 B, XOR-swizzled

    const int t    = threadIdx.x;
    const int lane = t & 63;
    const int wave = t >> 6;                    // 0..7
    const int quad = lane >> 4;
    const int l15  = lane & 15;
    const int rh   = wave >> 2;                 // row half (0/1)
    const int cg   = wave & 3;                  // 64-col group (0..3)

    const int wide = *flag;
    const int r     = t >> 2;                   // edge row 0..127
    const int chunk = t & 3;                    // 16B slot within 64B slice-row
    const long e   = (long)blockIdx.x * 128 + r;
    const int si = src[e << wide], di = dst[e << wide];
    const float* pe = ef + e * 64;

    // ---- ef loads (slices 0,1): 4 uint4 ----
    uint4 efu[2][2];
    #pragma unroll
    for (int s = 0; s < 2; s++) {
        const float* p = pe + s * 32 + chunk * 8;
        efu[s][0] = *(const uint4*)p;
        efu[s][1] = *(const uint4*)(p + 4);
    }

    // ---- W1b preload ks=0,1 into rotating slots (this wave's 64 cols) ----
    const ushort* wbase = W1b + (cg * 64 + l15) * 320 + quad * 8;
    short8 bpre[3][4];
    #pragma unroll
    for (int in = 0; in < 4; in++)
        bpre[0][in] = *(const short8*)(wbase + in * 16 * 320);
    #pragma unroll
    for (int in = 0; in < 4; in++)
        bpre[1][in] = *(const short8*)(wbase + in * 16 * 320 + 32);

    // ---- node gathers + stage everything to LDS ----
    if constexpr (NFB) {
        const ushort* psb = nfb + (long)si * 128 + chunk * 8;
        const ushort* pdb = nfb + (long)di * 128 + chunk * 8;
        short8 g[8];
        #pragma unroll
        for (int i = 0; i < 4; i++) g[i]     = *(const short8*)(psb + i * 32);
        #pragma unroll
        for (int i = 0; i < 4; i++) g[4 + i] = *(const short8*)(pdb + i * 32);
        #pragma unroll
        for (int s = 0; s < 2; s++)
            *(short8*)&a_lds[aidx(s, r, chunk)] = cvtpair(efu[s][0], efu[s][1]);
        #pragma unroll
        for (int i = 0; i < 8; i++)
            *(short8*)&a_lds[aidx(2 + i, r, chunk)] = g[i];
    } else {
        const float* ps = nf + (long)si * 128 + chunk * 8;
        const float* pd = nf + (long)di * 128 + chunk * 8;
        uint4 pn[16];
        #pragma unroll
        for (int i = 0; i < 4; i++) {
            pn[i * 2]     = *(const uint4*)(ps + i * 32);
            pn[i * 2 + 1] = *(const uint4*)(ps + i * 32 + 4);
        }
        #pragma unroll
        for (int i = 0; i < 4; i++) {
            pn[8 + i * 2]     = *(const uint4*)(pd + i * 32);
            pn[8 + i * 2 + 1] = *(const uint4*)(pd + i * 32 + 4);
        }
        #pragma unroll
        for (int s = 0; s < 2; s++)
            *(short8*)&a_lds[aidx(s, r, chunk)] = cvtpair(efu[s][0], efu[s][1]);
        #pragma unroll
        for (int i = 0; i < 8; i++)
            *(short8*)&a_lds[aidx(2 + i, r, chunk)] =
                cvtpair(pn[i * 2], pn[i * 2 + 1]);
    }
    __syncthreads();                            // the ONLY barrier

    f32x4 acc[4][4];
    #pragma unroll
    for (int a = 0; a < 4; a++)
        #pragma unroll
        for (int b = 0; b < 4; b++)
            acc[a][b] = (f32x4){0.f, 0.f, 0.f, 0.f};

    #pragma unroll
    for (int ks = 0; ks < 10; ks++) {
        if (ks < 8) {                           // prefetch W1b ks+2 (2-deep)
            #pragma unroll
            for (int in = 0; in < 4; in++)
                bpre[(ks + 2) % 3][in] =
                    *(const short8*)(wbase + in * 16 * 320 + (ks + 2) * 32);
        }
        short8 afr[4];
        #pragma unroll
        for (int mb = 0; mb < 4; mb++)
            afr[mb] = *(const short8*)
                &a_lds[aidx(ks, rh * 64 + mb * 16 + l15, quad)];
        __builtin_amdgcn_s_setprio(1);
        #pragma unroll
        for (int mb = 0; mb < 4; mb++)
            #pragma unroll
            for (int in = 0; in < 4; in++)
                acc[mb][in] = __builtin_amdgcn_mfma_f32_16x16x32_bf16(
                    afr[mb], bpre[ks % 3][in], acc[mb][in], 0, 0, 0);
        __builtin_amdgcn_s_setprio(0);
    }

    // Stats on acc = z - b1 (b1 folded later; var shift-invariant).
    // C/D layout: col = lane&15, row = quad*4 + reg.  Two row-half waves
    // per col-group both atomicAdd their partial sums.
    const int slot = blockIdx.x & 15;
    #pragma unroll
    for (int in = 0; in < 4; in++) {
        const int col = cg * 64 + in * 16 + l15;
        float s = 0.f, q = 0.f;
        #pragma unroll
        for (int mb = 0; mb < 4; mb++)
            #pragma unroll
            for (int j = 0; j < 4; j++) {
                float v = acc[mb][in][j];
                s += v; q += v * v;
            }
        s += __shfl_xor(s, 16); s += __shfl_xor(s, 32);
        q += __shfl_xor(q, 16); q += __shfl_xor(q, 32);
        if (quad == 0) {
            atomicAdd(&g_sum[slot * 256 + col], s);
            atomicAdd(&g_sq[slot * 256 + col], q);
        }
    }
}

// ---------------- Kernel B (fallback path): fold stats into M / C ---------
__global__ __launch_bounds__(256) void fold_kernel(
    const float* __restrict__ gamma, const float* __restrict__ beta,
    const float* __restrict__ W1, const float* __restrict__ b1,
    const float* __restrict__ W2, const float* __restrict__ b2,
    const float* __restrict__ g_sum, const float* __restrict__ g_sq,
    ushort* __restrict__ Mbig, ushort* __restrict__ Mb,
    float* __restrict__ Mf, float* __restrict__ Cvec)
{
    __shared__ float a_sh[256][8];
    __shared__ float red[8];
    __shared__ float mk_sh[64][8];
    const int t = threadIdx.x;

    float ssum = 0.f, ssq = 0.f;
    #pragma unroll
    for (int s = 0; s < 16; s++) {
        ssum += g_sum[s * 256 + t];
        ssq  += g_sq[s * 256 + t];
    }
    const float invE   = 1.0f / (float)N_EDGES;
    const float mu_acc = ssum * invE;
    float var = ssq * invE - mu_acc * mu_acc;
    var = fmaxf(var, 0.f);
    const float b1v = b1[t];
    const float mu  = mu_acc + b1v;
    const float g   = gamma[t] * rsqrtf(var + 1e-5f);
    const float sh  = b1v * g + beta[t] - mu * g;

    if (t < 8) red[t] = 0.f;
    ((float*)mk_sh)[t] = 0.f;
    ((float*)mk_sh)[t + 256] = 0.f;
    __syncthreads();
    #pragma unroll
    for (int c = 0; c < 8; c++) {
        const float w = W2[c * 256 + t];
        a_sh[t][c] = w * g;
        if (blockIdx.x == 0) atomicAdd(&red[c], w * sh);
    }
    __syncthreads();

    const int k  = blockIdx.x * 64 + (t & 63);
    const int q4 = t >> 6;
    float m[8] = {0.f, 0.f, 0.f, 0.f, 0.f, 0.f, 0.f, 0.f};
    #pragma unroll 8
    for (int hh = q4 * 64; hh < q4 * 64 + 64; hh++) {
        const float w1 = W1[hh * 320 + k];
        #pragma unroll
        for (int c = 0; c < 8; c++) m[c] += a_sh[hh][c] * w1;
    }
    #pragma unroll
    for (int c = 0; c < 8; c++) atomicAdd(&mk_sh[t & 63][c], m[c]);
    __syncthreads();

    if (t < 64) {
        const int kk = blockIdx.x * 64 + t;
        #pragma unroll
        for (int c = 0; c < 8; c++) {
            const float mv = mk_sh[t][c];
            Mf[c * 320 + kk]   = mv;
            Mbig[c * 320 + kk] = f2bf(mv);
            if (kk < 64) Mb[c * 64 + kk] = f2bf(mv);
        }
        #pragma unroll
        for (int c = 8; c < 16; c++) {
            Mbig[c * 320 + kk] = 0;
            if (kk < 64) Mb[c * 64 + kk] = 0;
        }
    }
    if (blockIdx.x == 0) {
        if (t < 8)       Cvec[t] = b2[t] + red[t];
        else if (t < 16) Cvec[t] = 0.f;
    }
}

// ---------------- fold_nodeproj (big path): fold + node projection --------
__global__ __launch_bounds__(256) void fold_nodeproj_kernel(
    const float* __restrict__ gamma, const float* __restrict__ beta,
    const float* __restrict__ W1, const float* __restrict__ b1,
    const float* __restrict__ W2, const float* __restrict__ b2,
    const float* __restrict__ g_sum, const float* __restrict__ g_sq,
    const float* __restrict__ nf, ushort* __restrict__ Mb,
    float* __restrict__ Cvec, float* __restrict__ Ps, float* __restrict__ Pd)
{
    __shared__ float a_sh[256][8];
    __shared__ float red[8];
    __shared__ float Ms[8][128];
    __shared__ float Md[8][128];
    const int t = threadIdx.x;

    float ssum = 0.f, ssq = 0.f;
    #pragma unroll
    for (int s = 0; s < 16; s++) {
        ssum += g_sum[s * 256 + t];
        ssq  += g_sq[s * 256 + t];
    }
    const float invE   = 1.0f / (float)N_EDGES;
    const float mu_acc = ssum * invE;
    float var = ssq * invE - mu_acc * mu_acc;
    var = fmaxf(var, 0.f);
    const float b1v = b1[t];
    const float mu  = mu_acc + b1v;
    const float g   = gamma[t] * rsqrtf(var + 1e-5f);
    const float sh  = b1v * g + beta[t] - mu * g;

    if (t < 8) red[t] = 0.f;
    __syncthreads();
    #pragma unroll
    for (int c = 0; c < 8; c++) {
        const float w = W2[c * 256 + t];
        a_sh[t][c] = w * g;
        if (blockIdx.x == 0) atomicAdd(&red[c], w * sh);
    }
    __syncthreads();

    float m[8] = {0.f, 0.f, 0.f, 0.f, 0.f, 0.f, 0.f, 0.f};
    #pragma unroll 8
    for (int hh = 0; hh < 256; hh++) {
        const float w1 = W1[hh * 320 + 64 + t];
        #pragma unroll
        for (int c = 0; c < 8; c++) m[c] += a_sh[hh][c] * w1;
    }
    #pragma unroll
    for (int c = 0; c < 8; c++) {
        if (t < 128) Ms[c][t] = m[c];
        else         Md[c][t - 128] = m[c];
    }
    if (blockIdx.x == 0) {
        if (t < 64) {
            float mm[8] = {0.f, 0.f, 0.f, 0.f, 0.f, 0.f, 0.f, 0.f};
            #pragma unroll 8
            for (int hh = 0; hh < 256; hh++) {
                const float w1 = W1[hh * 320 + t];
                #pragma unroll
                for (int c = 0; c < 8; c++) mm[c] += a_sh[hh][c] * w1;
            }
            #pragma unroll
            for (int c = 0; c < 8; c++)  Mb[c * 64 + t] = f2bf(mm[c]);
            #pragma unroll
            for (int c = 8; c < 16; c++) Mb[c * 64 + t] = 0;
        }
        if (t < 8)       Cvec[t] = b2[t] + red[t];
        else if (t < 16) Cvec[t] = 0.f;
    }
    __syncthreads();

    const int n = blockIdx.x * 256 + t;
    if (n >= N_NODES) return;
    float as[8] = {0,0,0,0,0,0,0,0}, ad[8] = {0,0,0,0,0,0,0,0};
    #pragma unroll 4
    for (int k = 0; k < 128; k += 4) {
        const float4 v = *(const float4*)(nf + (long)n * 128 + k);
        #pragma unroll
        for (int c = 0; c < 8; c++) {
            const float4 ms = *(const float4*)&Ms[c][k];
            const float4 md = *(const float4*)&Md[c][k];
            as[c] += v.x * ms.x + v.y * ms.y + v.z * ms.z + v.w * ms.w;
            ad[c] += v.x * md.x + v.y * md.y + v.z * md.z + v.w * md.w;
        }
    }
    #pragma unroll
    for (int c = 0; c < 8; c++) {
        Ps[n * 8 + c] = as[c];
        Pd[n * 8 + c] = ad[c];
    }
}

// ---------------- Kernel P (fallback path): node projection tables --------
__global__ __launch_bounds__(256) void nodeproj_kernel(
    const float* __restrict__ nf, const float* __restrict__ Mf,
    float* __restrict__ Ps, float* __restrict__ Pd)
{
    __shared__ float Ms[8][128];
    __shared__ float Md[8][128];
    const int t = threadIdx.x;
    #pragma unroll
    for (int i = 0; i < 4; i++) {
        const int f = t + i * 256;
        Ms[f >> 7][f & 127] = Mf[(f >> 7) * 320 + 64  + (f & 127)];
        Md[f >> 7][f & 127] = Mf[(f >> 7) * 320 + 192 + (f & 127)];
    }
    __syncthreads();
    const int n = blockIdx.x * 256 + t;
    if (n >= N_NODES) return;
    float as[8] = {0,0,0,0,0,0,0,0}, ad[8] = {0,0,0,0,0,0,0,0};
    #pragma unroll 4
    for (int k = 0; k < 128; k += 4) {
        const float4 v = *(const float4*)(nf + (long)n * 128 + k);
        #pragma unroll
        for (int c = 0; c < 8; c++) {
            const float4 ms = *(const float4*)&Ms[c][k];
            const float4 md = *(const float4*)&Md[c][k];
            as[c] += v.x * ms.x + v.y * ms.y + v.z * ms.z + v.w * ms.w;
            ad[c] += v.x * md.x + v.y * md.y + v.z * md.z + v.w * md.w;
        }
    }
    #pragma unroll
    for (int c = 0; c < 8; c++) {
        Ps[n * 8 + c] = as[c];
        Pd[n * 8 + c] = ad[c];
    }
}

// ---------------- Kernel C (fast): ef GEMM + tables + log-softmax ----------
__global__ __launch_bounds__(256) void edge_out_kernel(
    const float* __restrict__ ef, const int* __restrict__ src,
    const int* __restrict__ dst, const int* __restrict__ flag,
    const ushort* __restrict__ Mb, const float* __restrict__ Ps,
    const float* __restrict__ Pd, const float* __restrict__ Cvec,
    float* __restrict__ out)
{
    __shared__ float x_sh[4][64][20];            // pad 20: aligned, no alias
    const int t    = threadIdx.x;
    const int lane = t & 63;
    const int wave = t >> 6;
    const int quad = lane >> 4;
    const int l15  = lane & 15;
    const int wide = *flag;
    const long eb  = (long)blockIdx.x * 256 + wave * 64;

    const long ei = (eb + lane) << wide;
    const int sidx = src[ei], didx = dst[ei];
    const float4 s0 = *(const float4*)(Ps + sidx * 8);
    const float4 s1 = *(const float4*)(Ps + sidx * 8 + 4);
    const float4 d0 = *(const float4*)(Pd + didx * 8);
    const float4 d1 = *(const float4*)(Pd + didx * 8 + 4);
    const float4 c0 = *(const float4*)(Cvec);
    const float4 c1 = *(const float4*)(Cvec + 4);

    uint4 ea[4][2], eb4[4][2];
    #pragma unroll
    for (int mb = 0; mb < 4; mb++)
        #pragma unroll
        for (int ks = 0; ks < 2; ks++) {
            const float* p = ef + (eb + mb * 16 + l15) * 64 + ks * 32 + quad * 8;
            ea[mb][ks]  = *(const uint4*)p;
            eb4[mb][ks] = *(const uint4*)(p + 4);
        }

    f32x4 acc[4];
    #pragma unroll
    for (int mb = 0; mb < 4; mb++) acc[mb] = (f32x4){0.f, 0.f, 0.f, 0.f};

    const ushort* bbase = Mb + l15 * 64 + quad * 8;
    #pragma unroll
    for (int ks = 0; ks < 2; ks++) {
        short8 bfr = *(const short8*)(bbase + ks * 32);
        #pragma unroll
        for (int mb = 0; mb < 4; mb++)
            acc[mb] = __builtin_amdgcn_mfma_f32_16x16x32_bf16(
                cvtpair(ea[mb][ks], eb4[mb][ks]), bfr, acc[mb], 0, 0, 0);
    }

    #pragma unroll
    for (int mb = 0; mb < 4; mb++)
        #pragma unroll
        for (int j = 0; j < 4; j++)
            x_sh[wave][mb * 16 + quad * 4 + j][l15] = acc[mb][j];
    __syncthreads();

    const float4 xa = *(const float4*)&x_sh[wave][lane][0];
    const float4 xb = *(const float4*)&x_sh[wave][lane][4];

    float x0 = xa.x + c0.x + s0.x + d0.x;
    float x1 = xa.y + c0.y + s0.y + d0.y;
    float x2 = xa.z + c0.z + s0.z + d0.z;
    float x3 = xa.w + c0.w + s0.w + d0.w;
    float x4 = xb.x + c1.x + s1.x + d1.x;
    float x5 = xb.y + c1.y + s1.y + d1.y;
    float x6 = xb.z + c1.z + s1.z + d1.z;
    float x7 = xb.w + c1.w + s1.w + d1.w;

    float m = fmaxf(fmaxf(fmaxf(x0, x1), fmaxf(x2, x3)),
                    fmaxf(fmaxf(x4, x5), fmaxf(x6, x7)));
    float sx = __expf(x0 - m) + __expf(x1 - m) + __expf(x2 - m) +
               __expf(x3 - m) + __expf(x4 - m) + __expf(x5 - m) +
               __expf(x6 - m) + __expf(x7 - m);
    const float l = m + __logf(sx);

    float* po = out + (eb + lane) * 8;
    float4 o0 = {x0 - l, x1 - l, x2 - l, x3 - l};
    float4 o1 = {x4 - l, x5 - l, x6 - l, x7 - l};
    *(float4*)po       = o0;
    *(float4*)(po + 4) = o1;
}

// ---------------- Kernel C (fallback): full gather --------------
__global__ __launch_bounds__(256) void out_kernel(
    const float* __restrict__ nf, const float* __restrict__ ef,
    const int* __restrict__ src, const int* __restrict__ dst,
    const int* __restrict__ flag, const ushort* __restrict__ M,
    const float* __restrict__ Cvec, float* __restrict__ out)
{
    const int t    = threadIdx.x;
    const int lane = t & 63;
    const int wave = t >> 6;
    const int quad = lane >> 4;
    const int l15  = lane & 15;
    const int wide = *flag;
    const long eb  = (long)blockIdx.x * 256 + wave * 64;

    const float* pe[4]; const float* ps[4]; const float* pd[4];
    #pragma unroll
    for (int mb = 0; mb < 4; mb++) {
        const long e  = eb + mb * 16 + l15;
        const int si = src[e << wide], di = dst[e << wide];
        pe[mb] = ef + e * 64;
        ps[mb] = nf + (long)si * 128;
        pd[mb] = nf + (long)di * 128;
    }
    f32x4 acc[4];
    #pragma unroll
    for (int mb = 0; mb < 4; mb++) acc[mb] = (f32x4){0.f, 0.f, 0.f, 0.f};
    const ushort* bbase = M + l15 * 320 + quad * 8;
    #pragma unroll
    for (int ks = 0; ks < 10; ks++) {
        const int k0 = ks * 32;
        short8 bfr = *(const short8*)(bbase + k0);
        const int koff = k0 + quad * 8;
        #pragma unroll
        for (int mb = 0; mb < 4; mb++) {
            const float* p = (ks < 2) ? (pe[mb] + koff)
                           : (ks < 6) ? (ps[mb] + (koff - 64))
                                      : (pd[mb] + (koff - 192));
            acc[mb] = __builtin_amdgcn_mfma_f32_16x16x32_bf16(
                cvt8(p), bfr, acc[mb], 0, 0, 0);
        }
    }
    const float bv = Cvec[l15];
    #pragma unroll
    for (int mb = 0; mb < 4; mb++)
        #pragma unroll
        for (int j = 0; j < 4; j++) {
            float x = acc[mb][j] + bv;
            float m = x;
            m = fmaxf(m, __shfl_xor(m, 1));
            m = fmaxf(m, __shfl_xor(m, 2));
            m = fmaxf(m, __shfl_xor(m, 4));
            float sx = __expf(x - m);
            sx += __shfl_xor(sx, 1);
            sx += __shfl_xor(sx, 2);
            sx += __shfl_xor(sx, 4);
            const float o = x - m - __logf(sx);
            if (l15 < 8)
                out[(eb + mb * 16 + quad * 4 + j) * 8 + l15] = o;
        }
}

extern "C" void kernel_launch(void* const* d_in, const int* in_sizes, int n_in,
                              void* d_out, int out_size, void* d_ws, size_t ws_size,
                              hipStream_t stream) {
    const float* nf    = (const float*)d_in[0];
    const float* ef    = (const float*)d_in[1];
    const int*   src   = (const int*)d_in[2];
    const int*   dst   = (const int*)d_in[3];
    const float* W1    = (const float*)d_in[4];
    const float* b1    = (const float*)d_in[5];
    const float* gamma = (const float*)d_in[6];
    const float* beta  = (const float*)d_in[7];
    const float* W2    = (const float*)d_in[8];
    const float* b2    = (const float*)d_in[9];

    char*   ws    = (char*)d_ws;
    float*  g_sum = (float*)(ws + WS_SUM);
    float*  g_sq  = (float*)(ws + WS_SQ);
    float*  Cvec  = (float*)(ws + WS_CVEC);
    int*    flag  = (int*)(ws + WS_FLAG);
    ushort* Mbig  = (ushort*)(ws + WS_MBIG);
    ushort* Mb    = (ushort*)(ws + WS_MB);
    float*  Mf    = (float*)(ws + WS_MF);
    ushort* W1b   = (ushort*)(ws + WS_W1B);
    float*  Ps    = (float*)(ws + WS_PS);
    float*  Pd    = (float*)(ws + WS_PD);
    ushort* nfb   = (ushort*)(ws + WS_NFB);
    float*  out   = (float*)d_out;

    const bool fast = ws_size >= (size_t)WS_FAST_NEED;
    const bool big  = ws_size >= (size_t)WS_BIG_NEED;

    if (big) {
        prep_all_kernel<<<3206, 256, 0, stream>>>(nf, W1, src, dst, nfb, W1b,
                                                  (float*)ws, flag);
        gemm1_stats_kernel<true><<<N_EDGES / 128, 512, 0, stream>>>(
            nf, nfb, ef, src, dst, W1b, flag, g_sum, g_sq);
        fold_nodeproj_kernel<<<(N_NODES + 255) / 256, 256, 0, stream>>>(
            gamma, beta, W1, b1, W2, b2, g_sum, g_sq, nf, Mb, Cvec, Ps, Pd);
        edge_out_kernel<<<N_EDGES / 256, 256, 0, stream>>>(ef, src, dst, flag,
                                                           Mb, Ps, Pd, Cvec, out);
    } else {
        hipMemsetAsync(ws, 0, 33280, stream);
        detect_kernel<<<1, 64, 0, stream>>>(src, dst, flag);
        prep_kernel<<<80, 256, 0, stream>>>(W1, W1b);
        gemm1_stats_kernel<false><<<N_EDGES / 128, 512, 0, stream>>>(
            nf, nfb, ef, src, dst, W1b, flag, g_sum, g_sq);
        fold_kernel<<<5, 256, 0, stream>>>(gamma, beta, W1, b1, W2, b2,
                                           g_sum, g_sq, Mbig, Mb, Mf, Cvec);
        if (fast) {
            nodeproj_kernel<<<(N_NODES + 255) / 256, 256, 0, stream>>>(nf, Mf, Ps, Pd);
            edge_out_kernel<<<N_EDGES / 256, 256, 0, stream>>>(ef, src, dst, flag,
                                                               Mb, Ps, Pd, Cvec, out);
        } else {
            out_kernel<<<N_EDGES / 256, 256, 0, stream>>>(nf, ef, src, dst, flag,
                                                          Mbig, Cvec, out);
        }
    }
}

// Round 8
// 516.223 us; speedup vs baseline: 1.9028x; 1.9028x over previous
//
#include <hip/hip_runtime.h>
#include <hip/hip_bf16.h>

// EdgePredictor: gather-concat -> Linear(320->256) -> BatchNorm(train) ->
// Linear(256->8) -> LogSoftmax.  All float tensors FP32; output FP32.
// Indices int32 or int64 -> runtime detect.
//
// Algebra: logits = h @ M^T + C,  M = W2*diag(g')*W1 (8x320).
// Split along concat:  logits_e = ef_e @ Me^T + Ps[src_e] + Pd[dst_e] + C
//   Ps = nf @ Ms^T, Pd = nf @ Md^T  (50000x8 tables)
//
// Big-ws fast path = 4 dispatches:
//   1. prep_all: nf->bf16, W1->bf16, zero stats, detect idx width
//   2. gemm1_stats: 128-edge x 256-col tile, 512 threads (8 waves x 32
//      cols = ROUND-5 PROVEN SHAPE), 80KB swizzled LDS, 2 blocks/CU,
//      one barrier, 2-deep B register prefetch.  Register budget at
//      launch_bounds(512,4) = 128/wave: acc 64 (AGPR) + bpre 24 + misc
//      ~ 120 -> fits (r7's c=4 variant demanded ~170 -> spilled, 3.5x).
//   3. fold_nodeproj: fold + node projection (x8-unrolled hh loops).
//   4. edge_out: ef GEMM (K=64 MFMA) + per-lane table gather; LDS-transpose
//      epilogue (pad 20), per-lane serial softmax, coalesced f4 stores.
// Round-6 lesson: stats table-memoization loses to MFMA recompute.
// Round-7 lesson: reshapes must pass explicit register accounting.
// Fallback paths for smaller ws kept.

#define N_EDGES 800000
#define N_NODES 50000

typedef __attribute__((ext_vector_type(8))) short short8;
typedef __attribute__((ext_vector_type(4))) float f32x4;

// ws layout (bytes)
#define WS_SUM   0         // 16 slots x 256 f32 = 16384
#define WS_SQ    16384     // 16384
#define WS_CVEC  32768     // 16 f32
#define WS_FLAG  32832     // 1 int (zero region ends at 33280)
#define WS_MBIG  33280     // 16 x 320 bf16 = 10240 (fallback path)
#define WS_MB    43520     // 16 x 64 bf16 = 2048 (edge part)
#define WS_MF    45568     // 8 x 320 f32 = 10240 (fallback path)
#define WS_W1B   55808     // 256 x 320 bf16 = 163840 -> 219648
#define WS_PS    262144    // 50000 x 8 f32 = 1600000
#define WS_PD    2097152   // 1600000
#define WS_NFB   4194304   // 50000 x 128 bf16 = 12800000 -> 16994304
#define WS_FAST_NEED (4u << 20)
#define WS_BIG_NEED  16994304u

__device__ __forceinline__ ushort f2bf(float f) {
    union { float f; unsigned int u; } x; x.f = f;
    unsigned int r = x.u + 0x7FFFu + ((x.u >> 16) & 1u);   // RNE
    return (ushort)(r >> 16);
}
__device__ __forceinline__ short8 cvt8(const float* __restrict__ p) {
    short8 r;
    #pragma unroll
    for (int i = 0; i < 8; i++) r[i] = (short)f2bf(p[i]);
    return r;
}
__device__ __forceinline__ short8 cvtpair(uint4 a, uint4 b) {
    unsigned int v[8] = {a.x, a.y, a.z, a.w, b.x, b.y, b.z, b.w};
    short8 r;
    #pragma unroll
    for (int i = 0; i < 8; i++) {
        unsigned int u = v[i];
        unsigned int rr = u + 0x7FFFu + ((u >> 16) & 1u);
        r[i] = (short)(rr >> 16);
    }
    return r;
}

// XOR-swizzled LDS index (ushort units) for slice s (0..9), row r (0..127),
// 16B-slot c (0..3).  Row stride 64B.  slot' = c ^ ((r>>1)&3): wave reads
// (16 rows x 4 quads) and wave writes (16 rows x 4 chunks) both uniform
// over banks.  Same function both sides; 0 conflicts measured (r2-r5).
__device__ __forceinline__ int aidx(int s, int r, int c) {
    return ((s * 128 + r) * 4 + (c ^ ((r >> 1) & 3))) * 8;
}

// -------- detect index width: int64 iff all sampled high words are zero ----
__global__ void detect_kernel(const int* __restrict__ src,
                              const int* __restrict__ dst, int* flag) {
    int t = threadIdx.x;
    int v = src[2 * t + 1] | dst[2 * t + 1];
    #pragma unroll
    for (int o = 32; o >= 1; o >>= 1) v |= __shfl_xor(v, o);
    if (t == 0) *flag = (v == 0) ? 1 : 0;
}

// -------- prep: W1 f32 -> bf16 (fallback path) --------
__global__ __launch_bounds__(256) void prep_kernel(const float* __restrict__ W1,
                                                   ushort* __restrict__ W1b) {
    const int i = (blockIdx.x * 256 + threadIdx.x) * 4;
    const float4 v = *(const float4*)(W1 + i);
    ushort4 o;
    o.x = f2bf(v.x); o.y = f2bf(v.y); o.z = f2bf(v.z); o.w = f2bf(v.w);
    *(ushort4*)(W1b + i) = o;
}

// -------- prep_all (big path): nf cvt + W1 cvt + zero + detect ------------
__global__ __launch_bounds__(256) void prep_all_kernel(
    const float* __restrict__ nf, const float* __restrict__ W1,
    const int* __restrict__ src, const int* __restrict__ dst,
    ushort* __restrict__ nfb, ushort* __restrict__ W1b,
    float* __restrict__ zreg, int* __restrict__ flag)
{
    const int t = threadIdx.x;
    const int b = blockIdx.x;
    if (b < 3125) {
        const long i = (long)b * 2048 + t * 8;
        const float4 v0 = *(const float4*)(nf + i);
        const float4 v1 = *(const float4*)(nf + i + 4);
        short8 o;
        o[0] = (short)f2bf(v0.x); o[1] = (short)f2bf(v0.y);
        o[2] = (short)f2bf(v0.z); o[3] = (short)f2bf(v0.w);
        o[4] = (short)f2bf(v1.x); o[5] = (short)f2bf(v1.y);
        o[6] = (short)f2bf(v1.z); o[7] = (short)f2bf(v1.w);
        *(short8*)(nfb + i) = o;
    } else if (b < 3205) {
        const int i = (b - 3125) * 1024 + t * 4;
        const float4 v = *(const float4*)(W1 + i);
        ushort4 o;
        o.x = f2bf(v.x); o.y = f2bf(v.y); o.z = f2bf(v.z); o.w = f2bf(v.w);
        *(ushort4*)(W1b + i) = o;
    } else {
        for (int i = t; i < 8320; i += 256) zreg[i] = 0.f;
        __syncthreads();
        if (t < 64) {
            int v = src[2 * t + 1] | dst[2 * t + 1];
            #pragma unroll
            for (int o = 32; o >= 1; o >>= 1) v |= __shfl_xor(v, o);
            if (t == 0) *flag = (v == 0) ? 1 : 0;
        }
    }
}

// ---------------- Kernel A: gather + GEMM1 + column stats ----------------
// grid 6250, block 512 (8 waves).  Tile 128 edges x 256 cols, K=320 in
// 10x32.  Each wave owns a 128x32 output stripe: per iter 8 ds_read +
// 2 B-loads (2-deep prefetch) + 16 MFMA.  LDS 80KB -> 2 blocks/CU ->
// 4 waves/SIMD.  (Round-5 proven configuration, reverted from r7 spill.)
template <bool NFB>
__global__ __launch_bounds__(512, 4) void gemm1_stats_kernel(
    const float* __restrict__ nf, const ushort* __restrict__ nfb,
    const float* __restrict__ ef,
    const int* __restrict__ src, const int* __restrict__ dst,
    const ushort* __restrict__ W1b, const int* __restrict__ flag,
    float* __restrict__ g_sum, float* __restrict__ g_sq)
{
    __shared__ ushort a_lds[10 * 128 * 32];     // 81920 B, XOR-swizzled

    const int t    = threadIdx.x;
    const int lane = t & 63;
    const int wave = t >> 6;                    // 0..7
    const int quad = lane >> 4;
    const int l15  = lane & 15;

    const int wide = *flag;
    const int r     = t >> 2;                   // edge row 0..127
    const int chunk = t & 3;                    // 16B slot within 64B slice-row
    const long e   = (long)blockIdx.x * 128 + r;
    const int si = src[e << wide], di = dst[e << wide];
    const float* pe = ef + e * 64;

    // ---- ef loads (slices 0,1): 4 uint4 ----
    uint4 efu[2][2];
    #pragma unroll
    for (int s = 0; s < 2; s++) {
        const float* p = pe + s * 32 + chunk * 8;
        efu[s][0] = *(const uint4*)p;
        efu[s][1] = *(const uint4*)(p + 4);
    }

    // ---- W1b preload ks=0,1 into rotating slots ----
    const ushort* wbase = W1b + (wave * 32 + l15) * 320 + quad * 8;
    short8 bpre[3][2];
    #pragma unroll
    for (int in = 0; in < 2; in++)
        bpre[0][in] = *(const short8*)(wbase + in * 16 * 320);
    #pragma unroll
    for (int in = 0; in < 2; in++)
        bpre[1][in] = *(const short8*)(wbase + in * 16 * 320 + 32);

    // ---- node gathers + stage everything to LDS ----
    if constexpr (NFB) {
        const ushort* psb = nfb + (long)si * 128 + chunk * 8;
        const ushort* pdb = nfb + (long)di * 128 + chunk * 8;
        short8 g[8];
        #pragma unroll
        for (int i = 0; i < 4; i++) g[i]     = *(const short8*)(psb + i * 32);
        #pragma unroll
        for (int i = 0; i < 4; i++) g[4 + i] = *(const short8*)(pdb + i * 32);
        #pragma unroll
        for (int s = 0; s < 2; s++)
            *(short8*)&a_lds[aidx(s, r, chunk)] = cvtpair(efu[s][0], efu[s][1]);
        #pragma unroll
        for (int i = 0; i < 8; i++)
            *(short8*)&a_lds[aidx(2 + i, r, chunk)] = g[i];
    } else {
        const float* ps = nf + (long)si * 128 + chunk * 8;
        const float* pd = nf + (long)di * 128 + chunk * 8;
        uint4 pn[16];
        #pragma unroll
        for (int i = 0; i < 4; i++) {
            pn[i * 2]     = *(const uint4*)(ps + i * 32);
            pn[i * 2 + 1] = *(const uint4*)(ps + i * 32 + 4);
        }
        #pragma unroll
        for (int i = 0; i < 4; i++) {
            pn[8 + i * 2]     = *(const uint4*)(pd + i * 32);
            pn[8 + i * 2 + 1] = *(const uint4*)(pd + i * 32 + 4);
        }
        #pragma unroll
        for (int s = 0; s < 2; s++)
            *(short8*)&a_lds[aidx(s, r, chunk)] = cvtpair(efu[s][0], efu[s][1]);
        #pragma unroll
        for (int i = 0; i < 8; i++)
            *(short8*)&a_lds[aidx(2 + i, r, chunk)] =
                cvtpair(pn[i * 2], pn[i * 2 + 1]);
    }
    __syncthreads();                            // the ONLY barrier

    f32x4 acc[8][2];
    #pragma unroll
    for (int mb = 0; mb < 8; mb++)
        #pragma unroll
        for (int in = 0; in < 2; in++)
            acc[mb][in] = (f32x4){0.f, 0.f, 0.f, 0.f};

    #pragma unroll
    for (int ks = 0; ks < 10; ks++) {
        if (ks < 8) {                           // prefetch W1b ks+2 (2-deep)
            #pragma unroll
            for (int in = 0; in < 2; in++)
                bpre[(ks + 2) % 3][in] =
                    *(const short8*)(wbase + in * 16 * 320 + (ks + 2) * 32);
        }
        __builtin_amdgcn_s_setprio(1);
        #pragma unroll
        for (int mb = 0; mb < 8; mb++) {
            short8 afr = *(const short8*)
                &a_lds[aidx(ks, mb * 16 + l15, quad)];
            #pragma unroll
            for (int in = 0; in < 2; in++)
                acc[mb][in] = __builtin_amdgcn_mfma_f32_16x16x32_bf16(
                    afr, bpre[ks % 3][in], acc[mb][in], 0, 0, 0);
        }
        __builtin_amdgcn_s_setprio(0);
    }

    // Stats on acc = z - b1 (b1 folded later; var shift-invariant).
    // C/D layout: col = lane&15, row = quad*4 + reg.
    const int slot = blockIdx.x & 15;
    #pragma unroll
    for (int in = 0; in < 2; in++) {
        const int col = wave * 32 + in * 16 + l15;
        float s = 0.f, q = 0.f;
        #pragma unroll
        for (int mb = 0; mb < 8; mb++)
            #pragma unroll
            for (int j = 0; j < 4; j++) {
                float v = acc[mb][in][j];
                s += v; q += v * v;
            }
        s += __shfl_xor(s, 16); s += __shfl_xor(s, 32);
        q += __shfl_xor(q, 16); q += __shfl_xor(q, 32);
        if (quad == 0) {
            atomicAdd(&g_sum[slot * 256 + col], s);
            atomicAdd(&g_sq[slot * 256 + col], q);
        }
    }
}

// ---------------- Kernel B (fallback path): fold stats into M / C ---------
__global__ __launch_bounds__(256) void fold_kernel(
    const float* __restrict__ gamma, const float* __restrict__ beta,
    const float* __restrict__ W1, const float* __restrict__ b1,
    const float* __restrict__ W2, const float* __restrict__ b2,
    const float* __restrict__ g_sum, const float* __restrict__ g_sq,
    ushort* __restrict__ Mbig, ushort* __restrict__ Mb,
    float* __restrict__ Mf, float* __restrict__ Cvec)
{
    __shared__ float a_sh[256][8];
    __shared__ float red[8];
    __shared__ float mk_sh[64][8];
    const int t = threadIdx.x;

    float ssum = 0.f, ssq = 0.f;
    #pragma unroll
    for (int s = 0; s < 16; s++) {
        ssum += g_sum[s * 256 + t];
        ssq  += g_sq[s * 256 + t];
    }
    const float invE   = 1.0f / (float)N_EDGES;
    const float mu_acc = ssum * invE;
    float var = ssq * invE - mu_acc * mu_acc;
    var = fmaxf(var, 0.f);
    const float b1v = b1[t];
    const float mu  = mu_acc + b1v;
    const float g   = gamma[t] * rsqrtf(var + 1e-5f);
    const float sh  = b1v * g + beta[t] - mu * g;

    if (t < 8) red[t] = 0.f;
    ((float*)mk_sh)[t] = 0.f;
    ((float*)mk_sh)[t + 256] = 0.f;
    __syncthreads();
    #pragma unroll
    for (int c = 0; c < 8; c++) {
        const float w = W2[c * 256 + t];
        a_sh[t][c] = w * g;
        if (blockIdx.x == 0) atomicAdd(&red[c], w * sh);
    }
    __syncthreads();

    const int k  = blockIdx.x * 64 + (t & 63);
    const int q4 = t >> 6;
    float m[8] = {0.f, 0.f, 0.f, 0.f, 0.f, 0.f, 0.f, 0.f};
    #pragma unroll 8
    for (int hh = q4 * 64; hh < q4 * 64 + 64; hh++) {
        const float w1 = W1[hh * 320 + k];
        #pragma unroll
        for (int c = 0; c < 8; c++) m[c] += a_sh[hh][c] * w1;
    }
    #pragma unroll
    for (int c = 0; c < 8; c++) atomicAdd(&mk_sh[t & 63][c], m[c]);
    __syncthreads();

    if (t < 64) {
        const int kk = blockIdx.x * 64 + t;
        #pragma unroll
        for (int c = 0; c < 8; c++) {
            const float mv = mk_sh[t][c];
            Mf[c * 320 + kk]   = mv;
            Mbig[c * 320 + kk] = f2bf(mv);
            if (kk < 64) Mb[c * 64 + kk] = f2bf(mv);
        }
        #pragma unroll
        for (int c = 8; c < 16; c++) {
            Mbig[c * 320 + kk] = 0;
            if (kk < 64) Mb[c * 64 + kk] = 0;
        }
    }
    if (blockIdx.x == 0) {
        if (t < 8)       Cvec[t] = b2[t] + red[t];
        else if (t < 16) Cvec[t] = 0.f;
    }
}

// ---------------- fold_nodeproj (big path): fold + node projection --------
__global__ __launch_bounds__(256) void fold_nodeproj_kernel(
    const float* __restrict__ gamma, const float* __restrict__ beta,
    const float* __restrict__ W1, const float* __restrict__ b1,
    const float* __restrict__ W2, const float* __restrict__ b2,
    const float* __restrict__ g_sum, const float* __restrict__ g_sq,
    const float* __restrict__ nf, ushort* __restrict__ Mb,
    float* __restrict__ Cvec, float* __restrict__ Ps, float* __restrict__ Pd)
{
    __shared__ float a_sh[256][8];
    __shared__ float red[8];
    __shared__ float Ms[8][128];
    __shared__ float Md[8][128];
    const int t = threadIdx.x;

    float ssum = 0.f, ssq = 0.f;
    #pragma unroll
    for (int s = 0; s < 16; s++) {
        ssum += g_sum[s * 256 + t];
        ssq  += g_sq[s * 256 + t];
    }
    const float invE   = 1.0f / (float)N_EDGES;
    const float mu_acc = ssum * invE;
    float var = ssq * invE - mu_acc * mu_acc;
    var = fmaxf(var, 0.f);
    const float b1v = b1[t];
    const float mu  = mu_acc + b1v;
    const float g   = gamma[t] * rsqrtf(var + 1e-5f);
    const float sh  = b1v * g + beta[t] - mu * g;

    if (t < 8) red[t] = 0.f;
    __syncthreads();
    #pragma unroll
    for (int c = 0; c < 8; c++) {
        const float w = W2[c * 256 + t];
        a_sh[t][c] = w * g;
        if (blockIdx.x == 0) atomicAdd(&red[c], w * sh);
    }
    __syncthreads();

    float m[8] = {0.f, 0.f, 0.f, 0.f, 0.f, 0.f, 0.f, 0.f};
    #pragma unroll 8
    for (int hh = 0; hh < 256; hh++) {
        const float w1 = W1[hh * 320 + 64 + t];
        #pragma unroll
        for (int c = 0; c < 8; c++) m[c] += a_sh[hh][c] * w1;
    }
    #pragma unroll
    for (int c = 0; c < 8; c++) {
        if (t < 128) Ms[c][t] = m[c];
        else         Md[c][t - 128] = m[c];
    }
    if (blockIdx.x == 0) {
        if (t < 64) {
            float mm[8] = {0.f, 0.f, 0.f, 0.f, 0.f, 0.f, 0.f, 0.f};
            #pragma unroll 8
            for (int hh = 0; hh < 256; hh++) {
                const float w1 = W1[hh * 320 + t];
                #pragma unroll
                for (int c = 0; c < 8; c++) mm[c] += a_sh[hh][c] * w1;
            }
            #pragma unroll
            for (int c = 0; c < 8; c++)  Mb[c * 64 + t] = f2bf(mm[c]);
            #pragma unroll
            for (int c = 8; c < 16; c++) Mb[c * 64 + t] = 0;
        }
        if (t < 8)       Cvec[t] = b2[t] + red[t];
        else if (t < 16) Cvec[t] = 0.f;
    }
    __syncthreads();

    const int n = blockIdx.x * 256 + t;
    if (n >= N_NODES) return;
    float as[8] = {0,0,0,0,0,0,0,0}, ad[8] = {0,0,0,0,0,0,0,0};
    #pragma unroll 4
    for (int k = 0; k < 128; k += 4) {
        const float4 v = *(const float4*)(nf + (long)n * 128 + k);
        #pragma unroll
        for (int c = 0; c < 8; c++) {
            const float4 ms = *(const float4*)&Ms[c][k];
            const float4 md = *(const float4*)&Md[c][k];
            as[c] += v.x * ms.x + v.y * ms.y + v.z * ms.z + v.w * ms.w;
            ad[c] += v.x * md.x + v.y * md.y + v.z * md.z + v.w * md.w;
        }
    }
    #pragma unroll
    for (int c = 0; c < 8; c++) {
        Ps[n * 8 + c] = as[c];
        Pd[n * 8 + c] = ad[c];
    }
}

// ---------------- Kernel P (fallback path): node projection tables --------
__global__ __launch_bounds__(256) void nodeproj_kernel(
    const float* __restrict__ nf, const float* __restrict__ Mf,
    float* __restrict__ Ps, float* __restrict__ Pd)
{
    __shared__ float Ms[8][128];
    __shared__ float Md[8][128];
    const int t = threadIdx.x;
    #pragma unroll
    for (int i = 0; i < 4; i++) {
        const int f = t + i * 256;
        Ms[f >> 7][f & 127] = Mf[(f >> 7) * 320 + 64  + (f & 127)];
        Md[f >> 7][f & 127] = Mf[(f >> 7) * 320 + 192 + (f & 127)];
    }
    __syncthreads();
    const int n = blockIdx.x * 256 + t;
    if (n >= N_NODES) return;
    float as[8] = {0,0,0,0,0,0,0,0}, ad[8] = {0,0,0,0,0,0,0,0};
    #pragma unroll 4
    for (int k = 0; k < 128; k += 4) {
        const float4 v = *(const float4*)(nf + (long)n * 128 + k);
        #pragma unroll
        for (int c = 0; c < 8; c++) {
            const float4 ms = *(const float4*)&Ms[c][k];
            const float4 md = *(const float4*)&Md[c][k];
            as[c] += v.x * ms.x + v.y * ms.y + v.z * ms.z + v.w * ms.w;
            ad[c] += v.x * md.x + v.y * md.y + v.z * md.z + v.w * md.w;
        }
    }
    #pragma unroll
    for (int c = 0; c < 8; c++) {
        Ps[n * 8 + c] = as[c];
        Pd[n * 8 + c] = ad[c];
    }
}

// ---------------- Kernel C (fast): ef GEMM + tables + log-softmax ----------
__global__ __launch_bounds__(256) void edge_out_kernel(
    const float* __restrict__ ef, const int* __restrict__ src,
    const int* __restrict__ dst, const int* __restrict__ flag,
    const ushort* __restrict__ Mb, const float* __restrict__ Ps,
    const float* __restrict__ Pd, const float* __restrict__ Cvec,
    float* __restrict__ out)
{
    __shared__ float x_sh[4][64][20];            // pad 20: aligned, no alias
    const int t    = threadIdx.x;
    const int lane = t & 63;
    const int wave = t >> 6;
    const int quad = lane >> 4;
    const int l15  = lane & 15;
    const int wide = *flag;
    const long eb  = (long)blockIdx.x * 256 + wave * 64;

    const long ei = (eb + lane) << wide;
    const int sidx = src[ei], didx = dst[ei];
    const float4 s0 = *(const float4*)(Ps + sidx * 8);
    const float4 s1 = *(const float4*)(Ps + sidx * 8 + 4);
    const float4 d0 = *(const float4*)(Pd + didx * 8);
    const float4 d1 = *(const float4*)(Pd + didx * 8 + 4);
    const float4 c0 = *(const float4*)(Cvec);
    const float4 c1 = *(const float4*)(Cvec + 4);

    uint4 ea[4][2], eb4[4][2];
    #pragma unroll
    for (int mb = 0; mb < 4; mb++)
        #pragma unroll
        for (int ks = 0; ks < 2; ks++) {
            const float* p = ef + (eb + mb * 16 + l15) * 64 + ks * 32 + quad * 8;
            ea[mb][ks]  = *(const uint4*)p;
            eb4[mb][ks] = *(const uint4*)(p + 4);
        }

    f32x4 acc[4];
    #pragma unroll
    for (int mb = 0; mb < 4; mb++) acc[mb] = (f32x4){0.f, 0.f, 0.f, 0.f};

    const ushort* bbase = Mb + l15 * 64 + quad * 8;
    #pragma unroll
    for (int ks = 0; ks < 2; ks++) {
        short8 bfr = *(const short8*)(bbase + ks * 32);
        #pragma unroll
        for (int mb = 0; mb < 4; mb++)
            acc[mb] = __builtin_amdgcn_mfma_f32_16x16x32_bf16(
                cvtpair(ea[mb][ks], eb4[mb][ks]), bfr, acc[mb], 0, 0, 0);
    }

    #pragma unroll
    for (int mb = 0; mb < 4; mb++)
        #pragma unroll
        for (int j = 0; j < 4; j++)
            x_sh[wave][mb * 16 + quad * 4 + j][l15] = acc[mb][j];
    __syncthreads();

    const float4 xa = *(const float4*)&x_sh[wave][lane][0];
    const float4 xb = *(const float4*)&x_sh[wave][lane][4];

    float x0 = xa.x + c0.x + s0.x + d0.x;
    float x1 = xa.y + c0.y + s0.y + d0.y;
    float x2 = xa.z + c0.z + s0.z + d0.z;
    float x3 = xa.w + c0.w + s0.w + d0.w;
    float x4 = xb.x + c1.x + s1.x + d1.x;
    float x5 = xb.y + c1.y + s1.y + d1.y;
    float x6 = xb.z + c1.z + s1.z + d1.z;
    float x7 = xb.w + c1.w + s1.w + d1.w;

    float m = fmaxf(fmaxf(fmaxf(x0, x1), fmaxf(x2, x3)),
                    fmaxf(fmaxf(x4, x5), fmaxf(x6, x7)));
    float sx = __expf(x0 - m) + __expf(x1 - m) + __expf(x2 - m) +
               __expf(x3 - m) + __expf(x4 - m) + __expf(x5 - m) +
               __expf(x6 - m) + __expf(x7 - m);
    const float l = m + __logf(sx);

    float* po = out + (eb + lane) * 8;
    float4 o0 = {x0 - l, x1 - l, x2 - l, x3 - l};
    float4 o1 = {x4 - l, x5 - l, x6 - l, x7 - l};
    *(float4*)po       = o0;
    *(float4*)(po + 4) = o1;
}

// ---------------- Kernel C (fallback): full gather --------------
__global__ __launch_bounds__(256) void out_kernel(
    const float* __restrict__ nf, const float* __restrict__ ef,
    const int* __restrict__ src, const int* __restrict__ dst,
    const int* __restrict__ flag, const ushort* __restrict__ M,
    const float* __restrict__ Cvec, float* __restrict__ out)
{
    const int t    = threadIdx.x;
    const int lane = t & 63;
    const int wave = t >> 6;
    const int quad = lane >> 4;
    const int l15  = lane & 15;
    const int wide = *flag;
    const long eb  = (long)blockIdx.x * 256 + wave * 64;

    const float* pe[4]; const float* ps[4]; const float* pd[4];
    #pragma unroll
    for (int mb = 0; mb < 4; mb++) {
        const long e  = eb + mb * 16 + l15;
        const int si = src[e << wide], di = dst[e << wide];
        pe[mb] = ef + e * 64;
        ps[mb] = nf + (long)si * 128;
        pd[mb] = nf + (long)di * 128;
    }
    f32x4 acc[4];
    #pragma unroll
    for (int mb = 0; mb < 4; mb++) acc[mb] = (f32x4){0.f, 0.f, 0.f, 0.f};
    const ushort* bbase = M + l15 * 320 + quad * 8;
    #pragma unroll
    for (int ks = 0; ks < 10; ks++) {
        const int k0 = ks * 32;
        short8 bfr = *(const short8*)(bbase + k0);
        const int koff = k0 + quad * 8;
        #pragma unroll
        for (int mb = 0; mb < 4; mb++) {
            const float* p = (ks < 2) ? (pe[mb] + koff)
                           : (ks < 6) ? (ps[mb] + (koff - 64))
                                      : (pd[mb] + (koff - 192));
            acc[mb] = __builtin_amdgcn_mfma_f32_16x16x32_bf16(
                cvt8(p), bfr, acc[mb], 0, 0, 0);
        }
    }
    const float bv = Cvec[l15];
    #pragma unroll
    for (int mb = 0; mb < 4; mb++)
        #pragma unroll
        for (int j = 0; j < 4; j++) {
            float x = acc[mb][j] + bv;
            float m = x;
            m = fmaxf(m, __shfl_xor(m, 1));
            m = fmaxf(m, __shfl_xor(m, 2));
            m = fmaxf(m, __shfl_xor(m, 4));
            float sx = __expf(x - m);
            sx += __shfl_xor(sx, 1);
            sx += __shfl_xor(sx, 2);
            sx += __shfl_xor(sx, 4);
            const float o = x - m - __logf(sx);
            if (l15 < 8)
                out[(eb + mb * 16 + quad * 4 + j) * 8 + l15] = o;
        }
}

extern "C" void kernel_launch(void* const* d_in, const int* in_sizes, int n_in,
                              void* d_out, int out_size, void* d_ws, size_t ws_size,
                              hipStream_t stream) {
    const float* nf    = (const float*)d_in[0];
    const float* ef    = (const float*)d_in[1];
    const int*   src   = (const int*)d_in[2];
    const int*   dst   = (const int*)d_in[3];
    const float* W1    = (const float*)d_in[4];
    const float* b1    = (const float*)d_in[5];
    const float* gamma = (const float*)d_in[6];
    const float* beta  = (const float*)d_in[7];
    const float* W2    = (const float*)d_in[8];
    const float* b2    = (const float*)d_in[9];

    char*   ws    = (char*)d_ws;
    float*  g_sum = (float*)(ws + WS_SUM);
    float*  g_sq  = (float*)(ws + WS_SQ);
    float*  Cvec  = (float*)(ws + WS_CVEC);
    int*    flag  = (int*)(ws + WS_FLAG);
    ushort* Mbig  = (ushort*)(ws + WS_MBIG);
    ushort* Mb    = (ushort*)(ws + WS_MB);
    float*  Mf    = (float*)(ws + WS_MF);
    ushort* W1b   = (ushort*)(ws + WS_W1B);
    float*  Ps    = (float*)(ws + WS_PS);
    float*  Pd    = (float*)(ws + WS_PD);
    ushort* nfb   = (ushort*)(ws + WS_NFB);
    float*  out   = (float*)d_out;

    const bool fast = ws_size >= (size_t)WS_FAST_NEED;
    const bool big  = ws_size >= (size_t)WS_BIG_NEED;

    if (big) {
        prep_all_kernel<<<3206, 256, 0, stream>>>(nf, W1, src, dst, nfb, W1b,
                                                  (float*)ws, flag);
        gemm1_stats_kernel<true><<<N_EDGES / 128, 512, 0, stream>>>(
            nf, nfb, ef, src, dst, W1b, flag, g_sum, g_sq);
        fold_nodeproj_kernel<<<(N_NODES + 255) / 256, 256, 0, stream>>>(
            gamma, beta, W1, b1, W2, b2, g_sum, g_sq, nf, Mb, Cvec, Ps, Pd);
        edge_out_kernel<<<N_EDGES / 256, 256, 0, stream>>>(ef, src, dst, flag,
                                                           Mb, Ps, Pd, Cvec, out);
    } else {
        hipMemsetAsync(ws, 0, 33280, stream);
        detect_kernel<<<1, 64, 0, stream>>>(src, dst, flag);
        prep_kernel<<<80, 256, 0, stream>>>(W1, W1b);
        gemm1_stats_kernel<false><<<N_EDGES / 128, 512, 0, stream>>>(
            nf, nfb, ef, src, dst, W1b, flag, g_sum, g_sq);
        fold_kernel<<<5, 256, 0, stream>>>(gamma, beta, W1, b1, W2, b2,
                                           g_sum, g_sq, Mbig, Mb, Mf, Cvec);
        if (fast) {
            nodeproj_kernel<<<(N_NODES + 255) / 256, 256, 0, stream>>>(nf, Mf, Ps, Pd);
            edge_out_kernel<<<N_EDGES / 256, 256, 0, stream>>>(ef, src, dst, flag,
                                                               Mb, Ps, Pd, Cvec, out);
        } else {
            out_kernel<<<N_EDGES / 256, 256, 0, stream>>>(nf, ef, src, dst, flag,
                                                          Mbig, Cvec, out);
        }
    }
}